// Round 7
// baseline (207.638 us; speedup 1.0000x reference)
//
#include <hip/hip_runtime.h>
#include <hip/hip_bf16.h>
#include <cstdint>
#include <math.h>

// Problem constants
#define T_  4
#define B_  32
#define C_  384
#define HF_ 1536
#define HW_ 196
#define E_  8
#define N_  128
#define NROW 1792          // (n,h) units
#define NGT  50176         // (pair,pos) tasks = 256*196
#define LCAP 64
#define NGRP 24            // 24 output-groups of 64 (matches rowmaxp tiles)

#define LIFW (B_ * C_ / 4)    // 3072 blocks, 4 waves each, wave per (b,c) row
#define TRB  (E_ * 12 * 24)   // 2304 transpose tiles
#define PRB  48
#define COMBB ((N_ * C_ * 49) / 256)   // 9408 combine blocks

// ---------------------------------------------------------------------------
// K1: LIF spike counts (wave-per-row, float4) + per-element expert "level"
//     (u8, packed uint stores) + BN-const folding + w1 transpose->bf16 +
//     per-(c,group) max partials (rowmaxp = the group certificate table).
// level(x) = #{e : x >= te[e]}, te[e] = min{y : y/tau_e - 1 >= 0} (exact,
// monotone divide walk; taus ascending => spike for expert e <=> level > e).
// ---------------------------------------------------------------------------
__global__ __launch_bounds__(256) void k_lifprep(
    const float* __restrict__ x, float* __restrict__ cnt,
    unsigned int* __restrict__ levels4,
    const float* __restrict__ w1, __hip_bfloat16* __restrict__ w1t,
    const float* b1, const float* g1, const float* be1,
    const float* m1, const float* v1,
    const float* b2, const float* g2, const float* be2,
    const float* m2, const float* v2,
    const float* taus,
    float* A, float* Bc, float* const2, float* inv2v,
    float* rowmaxp, int* header) {
  __shared__ float tile[64][33];
  int blk = blockIdx.x;
  int tid = threadIdx.x;

  if (blk < LIFW) {
    // ---- LIF + levels: one wave per (b,c) row; lane = 4 positions (float4) ----
    int lane = tid & 63, wave = tid >> 6;
    int bc = blk * 4 + wave;
    bool act = lane < 49;                       // 49 float4 = 196 positions
    // exact per-expert thresholds (uniform across lanes, cheap)
    float te[E_];
    #pragma unroll
    for (int e2 = 0; e2 < E_; ++e2) {
      float t = taus[e2];
      float y = t;                              // y/t == 1.0 -> satisfies
      #pragma unroll
      for (int it = 0; it < 4; ++it) {
        float cnd = __uint_as_float(__float_as_uint(y) - 1u);
        if (cnd / t - 1.0f >= 0.0f) y = cnd; else break;
      }
      te[e2] = y;
    }
    const float4* xr = (const float4*)x;
    size_t rb = (size_t)bc * 49 + (act ? lane : 0);
    const size_t ts4 = (size_t)B_ * C_ * 49;    // t-stride in float4s
    float4 v = {0.f, 0.f, 0.f, 0.f};
    unsigned int counts = 0;                    // 4 x 8-bit packed per-t counts
    unsigned int pk[T_];
    #pragma unroll
    for (int t = 0; t < T_; ++t) {
      float4 xv;
      if (act) xv = xr[rb + (size_t)t * ts4];
      else { xv.x = xv.y = xv.z = xv.w = -1e30f; }
      // levels from RAW x (independent of LIF chain)
      int l0 = 0, l1 = 0, l2 = 0, l3 = 0;
      #pragma unroll
      for (int e2 = 0; e2 < E_; ++e2) {
        l0 += (xv.x >= te[e2]) ? 1 : 0;
        l1 += (xv.y >= te[e2]) ? 1 : 0;
        l2 += (xv.z >= te[e2]) ? 1 : 0;
        l3 += (xv.w >= te[e2]) ? 1 : 0;
      }
      pk[t] = (unsigned int)l0 | ((unsigned int)l1 << 8) |
              ((unsigned int)l2 << 16) | ((unsigned int)l3 << 24);
      // LIF chain
      v.x = v.x + (xv.x - v.x) * 0.5f;          // tau=2.0
      v.y = v.y + (xv.y - v.y) * 0.5f;
      v.z = v.z + (xv.z - v.z) * 0.5f;
      v.w = v.w + (xv.w - v.w) * 0.5f;
      int cl = 0;
      if (v.x - 1.0f >= 0.0f) { v.x = 0.f; ++cl; }
      if (v.y - 1.0f >= 0.0f) { v.y = 0.f; ++cl; }
      if (v.z - 1.0f >= 0.0f) { v.z = 0.f; ++cl; }
      if (v.w - 1.0f >= 0.0f) { v.w = 0.f; ++cl; }
      counts += (unsigned int)cl << (8 * t);
    }
    if (act) {
      #pragma unroll
      for (int t = 0; t < T_; ++t)
        levels4[rb + (size_t)t * ts4] = pk[t];  // coalesced uint stores
    }
    #pragma unroll
    for (int off = 1; off < 64; off <<= 1)
      counts += (unsigned int)__shfl_xor((int)counts, off, 64);
    if (lane == 0) {
      #pragma unroll
      for (int t = 0; t < T_; ++t)
        cnt[(size_t)t * B_ * C_ + bc] = (float)((counts >> (8 * t)) & 0xffu);
    }
  } else if (blk < LIFW + TRB) {
    // ---- transpose w1 -> bf16 w1t + per-(c, group-of-64-outputs) max ----
    int rem = blk - LIFW;
    int e = rem / 288, r2 = rem % 288;
    int ct = r2 / 24, ot = r2 % 24;
    int c0 = ct * 32, o0 = ot * 64;
    int cl = tid & 31, olb = tid >> 5;
    #pragma unroll
    for (int it = 0; it < 8; ++it) {
      int ol = olb + it * 8;
      tile[ol][cl] = w1[(size_t)(e * HF_ + o0 + ol) * C_ + c0 + cl];
    }
    __syncthreads();
    int ol2 = tid & 63, clb = tid >> 6;
    #pragma unroll
    for (int it = 0; it < 8; ++it) {
      int cl2 = clb + it * 4;
      w1t[(size_t)(e * C_ + c0 + cl2) * HF_ + o0 + ol2] =
          __float2bfloat16(tile[ol2][cl2]);
    }
    // per-(c, ot) max |bf16(w1)| over this tile's 64 outputs (race-free partials)
    if (tid < 32) {
      float m = 0.f;
      for (int ol = 0; ol < 64; ++ol) {
        float bv = __bfloat162float(__float2bfloat16(tile[ol][tid]));
        m = fmaxf(m, fabsf(bv));
      }
      rowmaxp[(size_t)(e * C_ + c0 + tid) * NGRP + ot] = m;
    }
  } else {
    // ---- prep ----
    int idx = (blk - LIFW - TRB) * 256 + tid;
    if (idx < 64) header[idx] = 0;
    if (idx < E_ * HF_) {
      int e = idx / HF_;
      float inv = g1[idx] / sqrtf(v1[idx] + 1e-5f);
      float sh  = be1[idx] - m1[idx] * inv;
      A[idx]  = inv;
      Bc[idx] = inv * b1[idx] + sh - taus[e];
    }
    if (idx < E_ * C_) {
      float inv = g2[idx] / sqrtf(v2[idx] + 1e-5f);
      const2[idx] = b2[idx] * inv + (be2[idx] - m2[idx] * inv);
      inv2v[idx]  = inv;
    }
  }
}

// ---------------------------------------------------------------------------
// K2: router (blocks 0..N-1) + rowmax reduce (N..N+11) + per-group thresholds
//     thrg[e][g] and thrmin[e] (N+12)
// ---------------------------------------------------------------------------
__global__ __launch_bounds__(256) void k_router(
    const float* __restrict__ cnt, const float* __restrict__ rw,
    const float* rb, const float* rg, const float* rbeta,
    const float* rmean, const float* rvar,
    const float* __restrict__ const2,
    const float* __restrict__ rowmaxp, float* __restrict__ rowmax,
    const float* __restrict__ A, const float* __restrict__ Bc,
    float* __restrict__ thrmin, float* __restrict__ thrg,
    int* sel_e, float* sel_g, float* gsum, float* K,
    float* f_acc, float* p_acc) {
  __shared__ float sc[C_ + 256 + E_];
  __shared__ int s_i1, s_i2;
  __shared__ float s_g1, s_g2;
  int bid = blockIdx.x, tid = threadIdx.x;

  if (bid < N_) {
    int n = bid;
    float* part = sc + C_;
    float* lg = part + 256;
    for (int c = tid; c < C_; c += 256) sc[c] = cnt[(size_t)n * C_ + c];
    __syncthreads();
    {
      int e = tid >> 5, sub = tid & 31;
      float d = 0.f;
      for (int c = sub; c < C_; c += 32) d += rw[e * C_ + c] * sc[c];
      part[tid] = d;
    }
    __syncthreads();
    if (tid < E_) {
      float dot = 0.f;
      #pragma unroll
      for (int j = 0; j < 32; ++j) dot += part[tid * 32 + j];
      float inv = rg[tid] / sqrtf(rvar[tid] + 1e-5f);
      lg[tid] = (dot * (1.0f / HW_) + rb[tid]) * inv +
                (rbeta[tid] - rmean[tid] * inv);
    }
    __syncthreads();
    if (tid == 0) {
      float m = lg[0];
      for (int e = 1; e < E_; ++e) m = fmaxf(m, lg[e]);
      float pr[E_]; float s = 0.f;
      for (int e = 0; e < E_; ++e) { pr[e] = expf(lg[e] - m); s += pr[e]; }
      float invs = 1.0f / s;
      for (int e = 0; e < E_; ++e) pr[e] *= invs;
      int i1 = 0;
      for (int e = 1; e < E_; ++e) if (pr[e] > pr[i1]) i1 = e;
      int i2 = (i1 == 0) ? 1 : 0;
      for (int e = 0; e < E_; ++e) if (e != i1 && pr[e] > pr[i2]) i2 = e;
      float w = pr[i1] + pr[i2];
      float ga = pr[i1] / w, gb = pr[i2] / w;
      sel_e[2 * n] = i1; sel_e[2 * n + 1] = i2;
      sel_g[2 * n] = ga; sel_g[2 * n + 1] = gb;
      gsum[n] = ga + gb;
      s_i1 = i1; s_i2 = i2; s_g1 = ga; s_g2 = gb;
      atomicAdd(&f_acc[i1], 1.0f);
      atomicAdd(&f_acc[i2], 1.0f);
      for (int e = 0; e < E_; ++e) atomicAdd(&p_acc[e], pr[e]);
    }
    __syncthreads();
    int i1 = s_i1, i2 = s_i2; float ga = s_g1, gb = s_g2;
    for (int c = tid; c < C_; c += 256)
      K[(size_t)n * C_ + c] =
          ga * const2[i1 * C_ + c] + gb * const2[i2 * C_ + c];
  } else if (bid < N_ + 12) {
    // reduce rowmax partials: 3072 (e,c) entries
    int idx = (bid - N_) * 256 + tid;
    if (idx < E_ * C_) {
      float m = 0.f;
      #pragma unroll
      for (int t = 0; t < NGRP; ++t)
        m = fmaxf(m, rowmaxp[(size_t)idx * NGRP + t]);
      rowmax[idx] = m;
    }
  } else {
    // thrg[e][g] = min_{o in group g} thr_o ; thrmin[e] = min_g thrg[e][g]
    // thr_o = A!=0 ? -B/|A| : (B>=0 ? -inf : +inf)
    int lane = tid & 63, wv = tid >> 6;
    for (int e = 0; e < E_; ++e) {
      for (int g = wv; g < NGRP; g += 4) {
        int o = g * 64 + lane;
        float a = A[e * HF_ + o], b = Bc[e * HF_ + o];
        float thr = (a != 0.0f) ? (-b / fabsf(a))
                                : ((b >= 0.0f) ? -INFINITY : INFINITY);
        #pragma unroll
        for (int off = 1; off < 64; off <<= 1)
          thr = fminf(thr, __shfl_xor(thr, off, 64));
        if (lane == 0) thrg[e * NGRP + g] = thr;
      }
    }
    __syncthreads();
    if (tid < E_) {
      float m = INFINITY;
      for (int g = 0; g < NGRP; ++g) m = fminf(m, thrg[tid * NGRP + g]);
      thrmin[tid] = m;
    }
  }
}

// ---------------------------------------------------------------------------
// K3: blocks [0,NROW): per (n,h) stage LEVELS slice (5.4 KB LDS, [w][c] bytes),
//     build spike lists for 28 (expert,w) tasks via byte compare level > e;
//     certified bound-prune; survivors into a global queue. Block 0 writes aux.
//     blocks [NROW, NROW+COMBB): streaming combine out = gsum*x + K.
// ---------------------------------------------------------------------------
__global__ __launch_bounds__(256) void k_lists(
    const float* __restrict__ x, const unsigned char* __restrict__ levels,
    const int* __restrict__ sel_e,
    const float* __restrict__ rowmax, const float* __restrict__ thrmin,
    unsigned short* __restrict__ list16,
    int* __restrict__ queue, int* __restrict__ qcount,
    const float* __restrict__ f_acc, const float* __restrict__ p_acc,
    float* __restrict__ aux_out,
    const float* __restrict__ gsum, const float* __restrict__ K,
    float* __restrict__ out) {
  __shared__ unsigned char xs8[14 * C_];   // [w][c], 5376 B
  int bid = blockIdx.x, tid = threadIdx.x;

  if (bid >= NROW) {
    // ---- combine blocks: thread per float4, coalesced ----
    int idx = (bid - NROW) * 256 + tid;         // over N*C*49 float4s
    int nc = idx / 49;                          // (n,c) row
    float g = gsum[nc / C_];
    float kc = K[nc];
    float4 v = ((const float4*)x)[idx];
    v.x = g * v.x + kc;
    v.y = g * v.y + kc;
    v.z = g * v.z + kc;
    v.w = g * v.w + kc;
    ((float4*)out)[idx] = v;
    return;
  }

  int lane = tid & 63, wave = tid >> 6;
  int n = bid / 14, h = bid - n * 14;
  unsigned long long lmask = (1ull << lane) - 1ull;

  if (bid == 0 && tid == 0) {
    float s = 0.f;
    for (int e = 0; e < E_; ++e)
      s += (f_acc[e] * (1.0f / N_)) * (p_acc[e] * (1.0f / N_));
    *aux_out = 0.01f * E_ * s;
  }

  // stage levels[n, :, h, :] -> xs8[w][c]   (7 ushort loads per c-row)
  for (int c = tid; c < C_; c += 256) {
    const unsigned short* p =
        (const unsigned short*)(levels + (size_t)(n * C_ + c) * HW_ + h * 14);
    #pragma unroll
    for (int i = 0; i < 7; ++i) {
      unsigned short u = p[i];
      xs8[(2 * i) * C_ + c]     = (unsigned char)(u & 0xff);
      xs8[(2 * i + 1) * C_ + c] = (unsigned char)(u >> 8);
    }
  }
  __syncthreads();

  for (int t = wave; t < 28; t += 4) {
    int k = t / 14, w = t - k * 14;
    int pair = 2 * n + k;
    int e = sel_e[pair];
    const float* rme = rowmax + e * C_;
    unsigned long long masks[6];
    int nnz = 0;
    float myb = 0.f;
    #pragma unroll
    for (int cb = 0; cb < 6; ++cb) {
      int c = cb * 64 + lane;
      bool sp = ((int)xs8[w * C_ + c] > e);     // level > e  <=>  spike
      unsigned long long m = __ballot(sp);
      masks[cb] = m;
      if (sp) myb += rme[c];
      nnz += __popcll(m);
    }
    // wave-sum the bound (uniform after butterfly)
    #pragma unroll
    for (int off = 1; off < 64; off <<= 1) myb += __shfl_xor(myb, off, 64);
    bool prune = (myb < thrmin[e] - 1e-4f);
    if (!prune) {
      int tw = pair * 196 + h * 14 + w;
      size_t lbase = (size_t)tw * LCAP;
      int cum = 0;
      #pragma unroll
      for (int cb = 0; cb < 6; ++cb) {
        unsigned long long m = masks[cb];
        bool sp = (m >> lane) & 1ull;
        int pos = cum + __popcll(m & lmask);
        if (sp && pos < LCAP) list16[lbase + pos] = (unsigned short)(cb * 64 + lane);
        cum += __popcll(m);
      }
      if (lane == 0) {
        int nv = nnz < LCAP ? nnz : LCAP;
        int qi = atomicAdd(qcount, 1);
        queue[qi] = tw | (nv << 20);
      }
    }
  }
}

// ---------------------------------------------------------------------------
// K4: gather v2 — grid-stride over compacted queue; one wave per task.
// Step 1: lanes 0..23 accumulate 24 per-group certified bounds from rowmaxp
//         (nnz x 96B coalesced) and ballot vs thrg.
// Step 2: only passing groups (rare) compute the 64 real accs (128B/c row
//         segments) and test; fires applied in-place by the wave.
// ---------------------------------------------------------------------------
__global__ __launch_bounds__(256, 4) void k_gather(
    const __hip_bfloat16* __restrict__ w1t,
    const float* __restrict__ A, const float* __restrict__ Bc,
    const int* __restrict__ sel_e, const float* __restrict__ sel_g,
    const int* __restrict__ queue, const int* __restrict__ qcount,
    const unsigned short* __restrict__ list16,
    const float* __restrict__ grpmax, const float* __restrict__ thrg,
    const float* __restrict__ inv2v, const float* __restrict__ w2,
    float* __restrict__ out) {
  int nq = *qcount;
  int wid = blockIdx.x * 4 + (threadIdx.x >> 6);
  int lane = threadIdx.x & 63;
  int nwaves = gridDim.x * 4;

  for (int qi = wid; qi < nq; qi += nwaves) {
    int ent = queue[qi];
    int tw = ent & 0xFFFFF;
    int nnz = ent >> 20;
    int pair = tw / HW_, pos = tw - pair * HW_;
    int n = pair >> 1;
    int e = sel_e[pair];
    int lv = (int)list16[(size_t)tw * LCAP + lane];

    // ---- step 1: per-group certified bounds (lanes 0..23) ----
    bool actg = lane < NGRP;
    int gl = actg ? lane : 0;
    const float* gme = grpmax + (size_t)e * C_ * NGRP;
    float myb = 0.f;
    int j = 0;
    for (; j + 4 <= nnz; j += 4) {
      int c0 = __shfl(lv, j + 0), c1 = __shfl(lv, j + 1);
      int c2 = __shfl(lv, j + 2), c3 = __shfl(lv, j + 3);
      float a0 = gme[(size_t)c0 * NGRP + gl];
      float a1 = gme[(size_t)c1 * NGRP + gl];
      float a2 = gme[(size_t)c2 * NGRP + gl];
      float a3 = gme[(size_t)c3 * NGRP + gl];
      myb += (a0 + a1) + (a2 + a3);
    }
    for (; j < nnz; ++j) {
      int c0 = __shfl(lv, j);
      myb += gme[(size_t)c0 * NGRP + gl];
    }
    unsigned long long gmask =
        __ballot(actg && (myb >= thrg[e * NGRP + gl] - 1e-4f));

    // ---- step 2: process passing groups only ----
    while (gmask) {
      int g = __ffsll(gmask) - 1;
      gmask &= gmask - 1;
      int o = g * 64 + lane;
      const unsigned short* wcol =
          (const unsigned short*)w1t + (size_t)e * C_ * HF_ + o;
      float acc = 0.f;
      int j2 = 0;
      for (; j2 + 4 <= nnz; j2 += 4) {
        int c0 = __shfl(lv, j2 + 0), c1 = __shfl(lv, j2 + 1);
        int c2 = __shfl(lv, j2 + 2), c3 = __shfl(lv, j2 + 3);
        float b0 = __uint_as_float((unsigned)wcol[(size_t)c0 * HF_] << 16);
        float b1 = __uint_as_float((unsigned)wcol[(size_t)c1 * HF_] << 16);
        float b2 = __uint_as_float((unsigned)wcol[(size_t)c2 * HF_] << 16);
        float b3 = __uint_as_float((unsigned)wcol[(size_t)c3 * HF_] << 16);
        acc += (b0 + b1) + (b2 + b3);
      }
      for (; j2 < nnz; ++j2) {
        int c0 = __shfl(lv, j2);
        acc += __uint_as_float((unsigned)wcol[(size_t)c0 * HF_] << 16);
      }
      float av = A[e * HF_ + o], bv = Bc[e * HF_ + o];
      unsigned long long fm = __ballot(av * acc + bv >= 0.0f);
      while (fm) {                               // rare layer-2 spikes
        int b = __ffsll(fm) - 1;
        fm &= fm - 1;
        int oo = g * 64 + b;
        float gk = sel_g[pair];
        const float* w2r = w2 + (size_t)e * C_ * HF_ + oo;
        const float* ivr = inv2v + e * C_;
        for (int c = lane; c < C_; c += 64) {
          atomicAdd(&out[((size_t)(n * C_ + c)) * HW_ + pos],
                    gk * ivr[c] * w2r[(size_t)c * HF_]);
        }
      }
    }
  }
}

// ---------------------------------------------------------------------------
// Workspace layout (bytes), total ~27 MB
// ---------------------------------------------------------------------------
extern "C" void kernel_launch(void* const* d_in, const int* in_sizes, int n_in,
                              void* d_out, int out_size, void* d_ws, size_t ws_size,
                              hipStream_t stream) {
  const float* x       = (const float*)d_in[0];
  const float* rw      = (const float*)d_in[1];
  const float* rb      = (const float*)d_in[2];
  const float* r_gamma = (const float*)d_in[3];
  const float* r_beta  = (const float*)d_in[4];
  const float* r_mean  = (const float*)d_in[5];
  const float* r_var   = (const float*)d_in[6];
  const float* w1      = (const float*)d_in[7];
  const float* b1      = (const float*)d_in[8];
  const float* g1      = (const float*)d_in[9];
  const float* be1     = (const float*)d_in[10];
  const float* m1      = (const float*)d_in[11];
  const float* v1      = (const float*)d_in[12];
  const float* w2      = (const float*)d_in[13];
  const float* b2      = (const float*)d_in[14];
  const float* g2      = (const float*)d_in[15];
  const float* be2     = (const float*)d_in[16];
  const float* m2      = (const float*)d_in[17];
  const float* v2      = (const float*)d_in[18];
  const float* taus    = (const float*)d_in[19];
  float* out = (float*)d_out;

  char* ws = (char*)d_ws;
  int*   header = (int*)ws;           // [1]=queue count
  float* f_acc  = (float*)ws + 8;
  float* p_acc  = (float*)ws + 16;
  float* cnt    = (float*)(ws + 256);
  int*   sel_e  = (int*)(ws + 196864);
  float* sel_g  = (float*)(ws + 197888);
  float* gsum   = (float*)(ws + 198912);
  float* K      = (float*)(ws + 199424);
  float* A      = (float*)(ws + 396032);
  float* Bc     = (float*)(ws + 445184);
  float* const2 = (float*)(ws + 494336);
  float* inv2v  = (float*)(ws + 506624);
  __hip_bfloat16* w1t = (__hip_bfloat16*)(ws + 715520);
  int*   queue  = (int*)(ws + 10152704);
  unsigned short* list16 = (unsigned short*)(ws + 10353408);
  float* rowmaxp = (float*)(ws + 16775936);   // [(e*C+c)][24] group maxes
  float* rowmax  = (float*)(ws + 17070848);
  float* thrmin  = (float*)(ws + 17083136);   // 32 B
  float* thrg    = (float*)(ws + 17083200);   // 8*24*4 = 768 B
  unsigned char* levels = (unsigned char*)(ws + 17084416);  // 9633792 B
  int* qcount = header + 1;

  k_lifprep<<<LIFW + TRB + PRB, 256, 0, stream>>>(
      x, cnt, (unsigned int*)levels, w1, w1t,
      b1, g1, be1, m1, v1, b2, g2, be2, m2, v2, taus,
      A, Bc, const2, inv2v, rowmaxp, header);
  k_router<<<N_ + 13, 256, 0, stream>>>(
      cnt, rw, rb, r_gamma, r_beta, r_mean, r_var, const2,
      rowmaxp, rowmax, A, Bc, thrmin, thrg,
      sel_e, sel_g, gsum, K, f_acc, p_acc);
  k_lists<<<NROW + COMBB, 256, 0, stream>>>(
      x, levels, sel_e, rowmax, thrmin, list16, queue, qcount,
      f_acc, p_acc, out + (out_size - 1), gsum, K, out);
  k_gather<<<2048, 256, 0, stream>>>(
      w1t, A, Bc, sel_e, sel_g, queue, qcount, list16,
      rowmaxp, thrg, inv2v, w2, out);
}

// Round 8
// 202.940 us; speedup vs baseline: 1.0231x; 1.0231x over previous
//
#include <hip/hip_runtime.h>
#include <hip/hip_bf16.h>
#include <cstdint>
#include <math.h>

// Problem constants
#define T_  4
#define B_  32
#define C_  384
#define HF_ 1536
#define HW_ 196
#define E_  8
#define N_  128
#define NROW 1792          // (n,h) units
#define NGT  50176         // max tasks per expert bucket
#define LCAP 64
#define NGRP 24            // rowmaxp partial tiles per (e,c)

#define LIFW (B_ * C_ / 4)    // 3072 blocks, 4 waves each, wave per (b,c) row
#define TRB  (E_ * 12 * 24)   // 2304 transpose tiles
#define PRB  48
#define COMBB ((N_ * C_ * 49) / 256)   // 9408 combine blocks

// ---------------------------------------------------------------------------
// K1: LIF spike counts (wave-per-row, float4) + per-element expert "level"
//     (u8, packed uint stores) + BN-const folding + w1 transpose->bf16 +
//     rowmax partials.
// level(x) = #{e : x >= te[e]}, te[e] = min{y : y/tau_e - 1 >= 0} (exact,
// monotone divide walk; taus ascending => spike for expert e <=> level > e).
// ---------------------------------------------------------------------------
__global__ __launch_bounds__(256) void k_lifprep(
    const float* __restrict__ x, float* __restrict__ cnt,
    unsigned int* __restrict__ levels4,
    const float* __restrict__ w1, __hip_bfloat16* __restrict__ w1t,
    const float* b1, const float* g1, const float* be1,
    const float* m1, const float* v1,
    const float* b2, const float* g2, const float* be2,
    const float* m2, const float* v2,
    const float* taus,
    float* A, float* Bc, float* const2, float* inv2v,
    float* rowmaxp, int* header) {
  __shared__ float tile[64][33];
  int blk = blockIdx.x;
  int tid = threadIdx.x;

  if (blk < LIFW) {
    // ---- LIF + levels: one wave per (b,c) row; lane = 4 positions (float4) ----
    int lane = tid & 63, wave = tid >> 6;
    int bc = blk * 4 + wave;
    bool act = lane < 49;                       // 49 float4 = 196 positions
    float te[E_];
    #pragma unroll
    for (int e2 = 0; e2 < E_; ++e2) {
      float t = taus[e2];
      float y = t;                              // y/t == 1.0 -> satisfies
      #pragma unroll
      for (int it = 0; it < 4; ++it) {
        float cnd = __uint_as_float(__float_as_uint(y) - 1u);
        if (cnd / t - 1.0f >= 0.0f) y = cnd; else break;
      }
      te[e2] = y;
    }
    const float4* xr = (const float4*)x;
    size_t rb = (size_t)bc * 49 + (act ? lane : 0);
    const size_t ts4 = (size_t)B_ * C_ * 49;    // t-stride in float4s
    float4 v = {0.f, 0.f, 0.f, 0.f};
    unsigned int counts = 0;                    // 4 x 8-bit packed per-t counts
    unsigned int pk[T_];
    #pragma unroll
    for (int t = 0; t < T_; ++t) {
      float4 xv;
      if (act) xv = xr[rb + (size_t)t * ts4];
      else { xv.x = xv.y = xv.z = xv.w = -1e30f; }
      int l0 = 0, l1 = 0, l2 = 0, l3 = 0;
      #pragma unroll
      for (int e2 = 0; e2 < E_; ++e2) {
        l0 += (xv.x >= te[e2]) ? 1 : 0;
        l1 += (xv.y >= te[e2]) ? 1 : 0;
        l2 += (xv.z >= te[e2]) ? 1 : 0;
        l3 += (xv.w >= te[e2]) ? 1 : 0;
      }
      pk[t] = (unsigned int)l0 | ((unsigned int)l1 << 8) |
              ((unsigned int)l2 << 16) | ((unsigned int)l3 << 24);
      v.x = v.x + (xv.x - v.x) * 0.5f;          // tau=2.0
      v.y = v.y + (xv.y - v.y) * 0.5f;
      v.z = v.z + (xv.z - v.z) * 0.5f;
      v.w = v.w + (xv.w - v.w) * 0.5f;
      int cl = 0;
      if (v.x - 1.0f >= 0.0f) { v.x = 0.f; ++cl; }
      if (v.y - 1.0f >= 0.0f) { v.y = 0.f; ++cl; }
      if (v.z - 1.0f >= 0.0f) { v.z = 0.f; ++cl; }
      if (v.w - 1.0f >= 0.0f) { v.w = 0.f; ++cl; }
      counts += (unsigned int)cl << (8 * t);
    }
    if (act) {
      #pragma unroll
      for (int t = 0; t < T_; ++t)
        levels4[rb + (size_t)t * ts4] = pk[t];  // coalesced uint stores
    }
    #pragma unroll
    for (int off = 1; off < 64; off <<= 1)
      counts += (unsigned int)__shfl_xor((int)counts, off, 64);
    if (lane == 0) {
      #pragma unroll
      for (int t = 0; t < T_; ++t)
        cnt[(size_t)t * B_ * C_ + bc] = (float)((counts >> (8 * t)) & 0xffu);
    }
  } else if (blk < LIFW + TRB) {
    // ---- transpose w1 -> bf16 w1t + rowmax partials ----
    int rem = blk - LIFW;
    int e = rem / 288, r2 = rem % 288;
    int ct = r2 / 24, ot = r2 % 24;
    int c0 = ct * 32, o0 = ot * 64;
    int cl = tid & 31, olb = tid >> 5;
    #pragma unroll
    for (int it = 0; it < 8; ++it) {
      int ol = olb + it * 8;
      tile[ol][cl] = w1[(size_t)(e * HF_ + o0 + ol) * C_ + c0 + cl];
    }
    __syncthreads();
    int ol2 = tid & 63, clb = tid >> 6;
    #pragma unroll
    for (int it = 0; it < 8; ++it) {
      int cl2 = clb + it * 4;
      w1t[(size_t)(e * C_ + c0 + cl2) * HF_ + o0 + ol2] =
          __float2bfloat16(tile[ol2][cl2]);
    }
    if (tid < 32) {
      float m = 0.f;
      for (int ol = 0; ol < 64; ++ol) {
        float bv = __bfloat162float(__float2bfloat16(tile[ol][tid]));
        m = fmaxf(m, fabsf(bv));
      }
      rowmaxp[(size_t)(e * C_ + c0 + tid) * NGRP + ot] = m;
    }
  } else {
    // ---- prep ----
    int idx = (blk - LIFW - TRB) * 256 + tid;
    if (idx < 64) header[idx] = 0;
    if (idx < E_ * HF_) {
      int e = idx / HF_;
      float inv = g1[idx] / sqrtf(v1[idx] + 1e-5f);
      float sh  = be1[idx] - m1[idx] * inv;
      A[idx]  = inv;
      Bc[idx] = inv * b1[idx] + sh - taus[e];
    }
    if (idx < E_ * C_) {
      float inv = g2[idx] / sqrtf(v2[idx] + 1e-5f);
      const2[idx] = b2[idx] * inv + (be2[idx] - m2[idx] * inv);
      inv2v[idx]  = inv;
    }
  }
}

// ---------------------------------------------------------------------------
// K2: router (blocks 0..N-1) + rowmax reduce (N..N+11) + thrmin (N+12)
// ---------------------------------------------------------------------------
__global__ __launch_bounds__(256) void k_router(
    const float* __restrict__ cnt, const float* __restrict__ rw,
    const float* rb, const float* rg, const float* rbeta,
    const float* rmean, const float* rvar,
    const float* __restrict__ const2,
    const float* __restrict__ rowmaxp, float* __restrict__ rowmax,
    const float* __restrict__ A, const float* __restrict__ Bc,
    float* __restrict__ thrmin,
    int* sel_e, float* sel_g, float* gsum, float* K,
    float* f_acc, float* p_acc) {
  __shared__ float sc[C_ + 256 + E_];
  __shared__ int s_i1, s_i2;
  __shared__ float s_g1, s_g2;
  int bid = blockIdx.x, tid = threadIdx.x;

  if (bid < N_) {
    int n = bid;
    float* part = sc + C_;
    float* lg = part + 256;
    for (int c = tid; c < C_; c += 256) sc[c] = cnt[(size_t)n * C_ + c];
    __syncthreads();
    {
      int e = tid >> 5, sub = tid & 31;
      float d = 0.f;
      for (int c = sub; c < C_; c += 32) d += rw[e * C_ + c] * sc[c];
      part[tid] = d;
    }
    __syncthreads();
    if (tid < E_) {
      float dot = 0.f;
      #pragma unroll
      for (int j = 0; j < 32; ++j) dot += part[tid * 32 + j];
      float inv = rg[tid] / sqrtf(rvar[tid] + 1e-5f);
      lg[tid] = (dot * (1.0f / HW_) + rb[tid]) * inv +
                (rbeta[tid] - rmean[tid] * inv);
    }
    __syncthreads();
    if (tid == 0) {
      float m = lg[0];
      for (int e = 1; e < E_; ++e) m = fmaxf(m, lg[e]);
      float pr[E_]; float s = 0.f;
      for (int e = 0; e < E_; ++e) { pr[e] = expf(lg[e] - m); s += pr[e]; }
      float invs = 1.0f / s;
      for (int e = 0; e < E_; ++e) pr[e] *= invs;
      int i1 = 0;
      for (int e = 1; e < E_; ++e) if (pr[e] > pr[i1]) i1 = e;
      int i2 = (i1 == 0) ? 1 : 0;
      for (int e = 0; e < E_; ++e) if (e != i1 && pr[e] > pr[i2]) i2 = e;
      float w = pr[i1] + pr[i2];
      float ga = pr[i1] / w, gb = pr[i2] / w;
      sel_e[2 * n] = i1; sel_e[2 * n + 1] = i2;
      sel_g[2 * n] = ga; sel_g[2 * n + 1] = gb;
      gsum[n] = ga + gb;
      s_i1 = i1; s_i2 = i2; s_g1 = ga; s_g2 = gb;
      atomicAdd(&f_acc[i1], 1.0f);
      atomicAdd(&f_acc[i2], 1.0f);
      for (int e = 0; e < E_; ++e) atomicAdd(&p_acc[e], pr[e]);
    }
    __syncthreads();
    int i1 = s_i1, i2 = s_i2; float ga = s_g1, gb = s_g2;
    for (int c = tid; c < C_; c += 256)
      K[(size_t)n * C_ + c] =
          ga * const2[i1 * C_ + c] + gb * const2[i2 * C_ + c];
  } else if (bid < N_ + 12) {
    // reduce rowmax partials: 3072 (e,c) entries
    int idx = (bid - N_) * 256 + tid;
    if (idx < E_ * C_) {
      float m = 0.f;
      #pragma unroll
      for (int t = 0; t < NGRP; ++t)
        m = fmaxf(m, rowmaxp[(size_t)idx * NGRP + t]);
      rowmax[idx] = m;
    }
  } else {
    // thrmin[e] = min_o ( A!=0 ? -B/|A| : (B>=0 ? -inf : +inf) )
    float* red = sc;
    for (int e = 0; e < E_; ++e) {
      float m = INFINITY;
      for (int o = tid; o < HF_; o += 256) {
        float a = A[e * HF_ + o], b = Bc[e * HF_ + o];
        float thr = (a != 0.0f) ? (-b / fabsf(a))
                                : ((b >= 0.0f) ? -INFINITY : INFINITY);
        m = fminf(m, thr);
      }
      red[tid] = m;
      __syncthreads();
      for (int s = 128; s > 0; s >>= 1) {
        if (tid < s) red[tid] = fminf(red[tid], red[tid + s]);
        __syncthreads();
      }
      if (tid == 0) thrmin[e] = red[0];
      __syncthreads();
    }
  }
}

// ---------------------------------------------------------------------------
// K3: blocks [0,NROW): per (n,h) stage LEVELS slice (5.4 KB LDS, [w][c] bytes),
//     build spike lists for 28 (expert,w) tasks via byte compare level > e;
//     certified bound-prune; survivors into PER-EXPERT queue buckets.
//     Block 0 writes aux.
//     blocks [NROW, NROW+COMBB): streaming combine out = gsum*x + K.
// ---------------------------------------------------------------------------
__global__ __launch_bounds__(256) void k_lists(
    const float* __restrict__ x, const unsigned char* __restrict__ levels,
    const int* __restrict__ sel_e,
    const float* __restrict__ rowmax, const float* __restrict__ thrmin,
    unsigned short* __restrict__ list16,
    int* __restrict__ queue, int* __restrict__ qcount,
    const float* __restrict__ f_acc, const float* __restrict__ p_acc,
    float* __restrict__ aux_out,
    const float* __restrict__ gsum, const float* __restrict__ K,
    float* __restrict__ out) {
  __shared__ unsigned char xs8[14 * C_];   // [w][c], 5376 B
  int bid = blockIdx.x, tid = threadIdx.x;

  if (bid >= NROW) {
    // ---- combine blocks: thread per float4, coalesced ----
    int idx = (bid - NROW) * 256 + tid;         // over N*C*49 float4s
    int nc = idx / 49;                          // (n,c) row
    float g = gsum[nc / C_];
    float kc = K[nc];
    float4 v = ((const float4*)x)[idx];
    v.x = g * v.x + kc;
    v.y = g * v.y + kc;
    v.z = g * v.z + kc;
    v.w = g * v.w + kc;
    ((float4*)out)[idx] = v;
    return;
  }

  int lane = tid & 63, wave = tid >> 6;
  int n = bid / 14, h = bid - n * 14;
  unsigned long long lmask = (1ull << lane) - 1ull;

  if (bid == 0 && tid == 0) {
    float s = 0.f;
    for (int e = 0; e < E_; ++e)
      s += (f_acc[e] * (1.0f / N_)) * (p_acc[e] * (1.0f / N_));
    *aux_out = 0.01f * E_ * s;
  }

  // stage levels[n, :, h, :] -> xs8[w][c]   (7 ushort loads per c-row)
  for (int c = tid; c < C_; c += 256) {
    const unsigned short* p =
        (const unsigned short*)(levels + (size_t)(n * C_ + c) * HW_ + h * 14);
    #pragma unroll
    for (int i = 0; i < 7; ++i) {
      unsigned short u = p[i];
      xs8[(2 * i) * C_ + c]     = (unsigned char)(u & 0xff);
      xs8[(2 * i + 1) * C_ + c] = (unsigned char)(u >> 8);
    }
  }
  __syncthreads();

  for (int t = wave; t < 28; t += 4) {
    int k = t / 14, w = t - k * 14;
    int pair = 2 * n + k;
    int e = sel_e[pair];
    const float* rme = rowmax + e * C_;
    unsigned long long masks[6];
    int nnz = 0;
    float myb = 0.f;
    #pragma unroll
    for (int cb = 0; cb < 6; ++cb) {
      int c = cb * 64 + lane;
      bool sp = ((int)xs8[w * C_ + c] > e);     // level > e  <=>  spike
      unsigned long long m = __ballot(sp);
      masks[cb] = m;
      if (sp) myb += rme[c];
      nnz += __popcll(m);
    }
    // wave-sum the bound (uniform after butterfly)
    #pragma unroll
    for (int off = 1; off < 64; off <<= 1) myb += __shfl_xor(myb, off, 64);
    bool prune = (myb < thrmin[e] - 1e-4f);
    if (!prune) {
      int tw = pair * 196 + h * 14 + w;
      size_t lbase = (size_t)tw * LCAP;
      int cum = 0;
      #pragma unroll
      for (int cb = 0; cb < 6; ++cb) {
        unsigned long long m = masks[cb];
        bool sp = (m >> lane) & 1ull;
        int pos = cum + __popcll(m & lmask);
        if (sp && pos < LCAP) list16[lbase + pos] = (unsigned short)(cb * 64 + lane);
        cum += __popcll(m);
      }
      if (lane == 0) {
        int nv = nnz < LCAP ? nnz : LCAP;
        int qi = atomicAdd(&qcount[e], 1);
        queue[e * NGT + qi] = tw | (nv << 20);
      }
    }
  }
}

// ---------------------------------------------------------------------------
// K4: gather v3 — expert-bucketed queue, blocked contiguous chunk per wave
// (all XCDs process the same expert region concurrently -> per-XCD L2 holds
// one 1.18MB w1t slice). Single merged pass: 24 accs, 3 uint4 loads per c,
// j-unroll x2 (6 loads in flight). Rare layer-2 spikes applied in-place.
// ---------------------------------------------------------------------------
__global__ __launch_bounds__(256, 4) void k_gather(
    const __hip_bfloat16* __restrict__ w1t,
    const float* __restrict__ A, const float* __restrict__ Bc,
    const float* __restrict__ sel_g,
    const int* __restrict__ queue, const int* __restrict__ qcount,
    const unsigned short* __restrict__ list16,
    const float* __restrict__ inv2v, const float* __restrict__ w2,
    float* __restrict__ out) {
  int cum[E_ + 1];
  cum[0] = 0;
  #pragma unroll
  for (int e2 = 0; e2 < E_; ++e2) cum[e2 + 1] = cum[e2] + qcount[e2];
  int nq = cum[E_];
  int wid = blockIdx.x * 4 + (threadIdx.x >> 6);
  int lane = threadIdx.x & 63;
  int nwaves = gridDim.x * 4;
  int chunk = (nq + nwaves - 1) / nwaves;
  int start = wid * chunk;
  int end = start + chunk; if (end > nq) end = nq;

  for (int gidx = start; gidx < end; ++gidx) {
    // locate expert bucket (taus ascending; buckets contiguous)
    int e = 0;
    #pragma unroll
    for (int k = 1; k < E_; ++k) e += (gidx >= cum[k]) ? 1 : 0;
    int ent = queue[e * NGT + (gidx - cum[e])];
    int tw = ent & 0xFFFFF;
    int nnz = ent >> 20;
    int pair = tw / HW_, pos = tw - pair * HW_;
    int n = pair >> 1;
    int lv = (int)list16[(size_t)tw * LCAP + lane];
    const uint4* wb = (const uint4*)(w1t + (size_t)e * C_ * HF_);  // 192/row
    const uint4* wbp0 = wb + lane;
    const uint4* wbp1 = wb + 64 + lane;
    const uint4* wbp2 = wb + 128 + lane;

    float acc[24];
    #pragma unroll
    for (int q = 0; q < 24; ++q) acc[q] = 0.f;
    int j = 0;
    for (; j + 2 <= nnz; j += 2) {
      int c0 = __shfl(lv, j), c1 = __shfl(lv, j + 1);
      uint4 a0 = wbp0[c0 * 192];
      uint4 a1 = wbp1[c0 * 192];
      uint4 a2 = wbp2[c0 * 192];
      uint4 b0 = wbp0[c1 * 192];
      uint4 b1 = wbp1[c1 * 192];
      uint4 b2 = wbp2[c1 * 192];
      uint32_t uu[12] = {a0.x, a0.y, a0.z, a0.w, a1.x, a1.y, a1.z, a1.w,
                         a2.x, a2.y, a2.z, a2.w};
      uint32_t vv[12] = {b0.x, b0.y, b0.z, b0.w, b1.x, b1.y, b1.z, b1.w,
                         b2.x, b2.y, b2.z, b2.w};
      #pragma unroll
      for (int q = 0; q < 12; ++q) {
        acc[2 * q]     += __uint_as_float(uu[q] << 16) +
                          __uint_as_float(vv[q] << 16);
        acc[2 * q + 1] += __uint_as_float(uu[q] & 0xffff0000u) +
                          __uint_as_float(vv[q] & 0xffff0000u);
      }
    }
    for (; j < nnz; ++j) {
      int c0 = __shfl(lv, j);
      uint4 a0 = wbp0[c0 * 192];
      uint4 a1 = wbp1[c0 * 192];
      uint4 a2 = wbp2[c0 * 192];
      uint32_t uu[12] = {a0.x, a0.y, a0.z, a0.w, a1.x, a1.y, a1.z, a1.w,
                         a2.x, a2.y, a2.z, a2.w};
      #pragma unroll
      for (int q = 0; q < 12; ++q) {
        acc[2 * q]     += __uint_as_float(uu[q] << 16);
        acc[2 * q + 1] += __uint_as_float(uu[q] & 0xffff0000u);
      }
    }
    // threshold: o = (p*64+lane)*8 + q  for p in 0..2, acc index p*8+q
    #pragma unroll
    for (int p = 0; p < 3; ++p) {
      int k2 = (p * 64 + lane) * 2;
      float4 Av0 = ((const float4*)(A + e * HF_))[k2];
      float4 Av1 = ((const float4*)(A + e * HF_))[k2 + 1];
      float4 Bv0 = ((const float4*)(Bc + e * HF_))[k2];
      float4 Bv1 = ((const float4*)(Bc + e * HF_))[k2 + 1];
      float av[8] = {Av0.x, Av0.y, Av0.z, Av0.w, Av1.x, Av1.y, Av1.z, Av1.w};
      float bv[8] = {Bv0.x, Bv0.y, Bv0.z, Bv0.w, Bv1.x, Bv1.y, Bv1.z, Bv1.w};
      #pragma unroll
      for (int q = 0; q < 8; ++q) {
        unsigned long long fm = __ballot(av[q] * acc[p * 8 + q] + bv[q] >= 0.0f);
        while (fm) {                           // rare layer-2 spikes
          int b = __ffsll(fm) - 1;
          fm &= fm - 1;
          int oo = (p * 64 + b) * 8 + q;
          float gk = sel_g[pair];
          const float* w2r = w2 + (size_t)e * C_ * HF_ + oo;
          const float* ivr = inv2v + e * C_;
          for (int c = lane; c < C_; c += 64) {
            atomicAdd(&out[((size_t)(n * C_ + c)) * HW_ + pos],
                      gk * ivr[c] * w2r[(size_t)c * HF_]);
          }
        }
      }
    }
  }
}

// ---------------------------------------------------------------------------
// Workspace layout (bytes), total ~28.4 MB
// ---------------------------------------------------------------------------
extern "C" void kernel_launch(void* const* d_in, const int* in_sizes, int n_in,
                              void* d_out, int out_size, void* d_ws, size_t ws_size,
                              hipStream_t stream) {
  const float* x       = (const float*)d_in[0];
  const float* rw      = (const float*)d_in[1];
  const float* rb      = (const float*)d_in[2];
  const float* r_gamma = (const float*)d_in[3];
  const float* r_beta  = (const float*)d_in[4];
  const float* r_mean  = (const float*)d_in[5];
  const float* r_var   = (const float*)d_in[6];
  const float* w1      = (const float*)d_in[7];
  const float* b1      = (const float*)d_in[8];
  const float* g1      = (const float*)d_in[9];
  const float* be1     = (const float*)d_in[10];
  const float* m1      = (const float*)d_in[11];
  const float* v1      = (const float*)d_in[12];
  const float* w2      = (const float*)d_in[13];
  const float* b2      = (const float*)d_in[14];
  const float* g2      = (const float*)d_in[15];
  const float* be2     = (const float*)d_in[16];
  const float* m2      = (const float*)d_in[17];
  const float* v2      = (const float*)d_in[18];
  const float* taus    = (const float*)d_in[19];
  float* out = (float*)d_out;

  char* ws = (char*)d_ws;
  int*   header = (int*)ws;           // ints 24..31 = qcount[8]
  float* f_acc  = (float*)ws + 8;     // bytes 32..63
  float* p_acc  = (float*)ws + 16;    // bytes 64..95
  int*   qcount = header + 24;        // bytes 96..127 (zeroed by prep)
  float* cnt    = (float*)(ws + 256);
  int*   sel_e  = (int*)(ws + 196864);
  float* sel_g  = (float*)(ws + 197888);
  float* gsum   = (float*)(ws + 198912);
  float* K      = (float*)(ws + 199424);
  float* A      = (float*)(ws + 396032);
  float* Bc     = (float*)(ws + 445184);
  float* const2 = (float*)(ws + 494336);
  float* inv2v  = (float*)(ws + 506624);
  __hip_bfloat16* w1t = (__hip_bfloat16*)(ws + 715520);      // ends 10152704
  unsigned short* list16 = (unsigned short*)(ws + 10353408); // ends 16775936
  float* rowmaxp = (float*)(ws + 16775936);                  // ends 17070848
  float* rowmax  = (float*)(ws + 17070848);                  // ends 17083136
  float* thrmin  = (float*)(ws + 17083136);                  // 32 B
  unsigned char* levels = (unsigned char*)(ws + 17084416);   // ends 26718208
  int*   queue  = (int*)(ws + 26718208);                     // 8*NGT*4 = 1605632

  k_lifprep<<<LIFW + TRB + PRB, 256, 0, stream>>>(
      x, cnt, (unsigned int*)levels, w1, w1t,
      b1, g1, be1, m1, v1, b2, g2, be2, m2, v2, taus,
      A, Bc, const2, inv2v, rowmaxp, header);
  k_router<<<N_ + 13, 256, 0, stream>>>(
      cnt, rw, rb, r_gamma, r_beta, r_mean, r_var, const2,
      rowmaxp, rowmax, A, Bc, thrmin,
      sel_e, sel_g, gsum, K, f_acc, p_acc);
  k_lists<<<NROW + COMBB, 256, 0, stream>>>(
      x, levels, sel_e, rowmax, thrmin, list16, queue, qcount,
      f_acc, p_acc, out + (out_size - 1), gsum, K, out);
  k_gather<<<2048, 256, 0, stream>>>(
      w1t, A, Bc, sel_g, queue, qcount, list16, inv2v, w2, out);
}